// Round 5
// baseline (802.690 us; speedup 1.0000x reference)
//
#include <hip/hip_runtime.h>
#include <hip/hip_bf16.h>
#include <hip/hip_cooperative_groups.h>
#include <math.h>

namespace cg = cooperative_groups;

#define Nn 20000
#define Ee 320000
#define INF_ 256
#define Hh 4
#define Cc 64
#define HC 256
#define NB_ 79
#define NEG_SLOPE 0.2f

using frag16 = __attribute__((ext_vector_type(8))) short;   // 8 bf16 (4 VGPRs)
using f32x4  = __attribute__((ext_vector_type(4))) float;

// async global->LDS 16B per lane; LDS dest = wave-uniform base + lane*16
__device__ __forceinline__ void async16(const void* g, void* l) {
    __builtin_amdgcn_global_load_lds(
        (const __attribute__((address_space(1))) unsigned int*)g,
        (__attribute__((address_space(3))) unsigned int*)l,
        16, 0, 0);
}

// ---------------- bf16 split-precision helpers ----------------

__device__ inline unsigned short bf16rn(float f) {
    unsigned u = __float_as_uint(f);
    unsigned r = (u + 0x7FFFu + ((u >> 16) & 1u)) >> 16;   // RTNE
    return (unsigned short)r;
}

__device__ inline void split1(float v, short& h, short& l) {
    unsigned short hh = bf16rn(v);
    float back = __uint_as_float(((unsigned)hh) << 16);
    unsigned short ll = bf16rn(v - back);
    h = (short)hh; l = (short)ll;
}

__device__ __forceinline__ float4 bf4_to_f4(ushort4 u) {
    return make_float4(__uint_as_float((unsigned)u.x << 16),
                       __uint_as_float((unsigned)u.y << 16),
                       __uint_as_float((unsigned)u.z << 16),
                       __uint_as_float((unsigned)u.w << 16));
}

// ---------------- cooperative single-dispatch CSR build ----------------
// phases: init deg/gpart -> hist -> per-block scan -> block-sum scan ->
//         add offsets -> scatter. grid.sync() between phases.

__global__ __launch_bounds__(256) void csr_coop(const int* __restrict__ dstv,
                                                const int* __restrict__ srcv,
                                                int* deg, int* row_start,
                                                int* cursor, int* colx,
                                                int* bsum, int* boff,
                                                float* gpart) {
    cg::grid_group grid = cg::this_grid();
    int tid = threadIdx.x;
    int gid0 = blockIdx.x * 256 + tid;
    int stride = gridDim.x * 256;

    // phase 1: init (deg=1 pre-counts self-loop; zero pooling partials)
    for (int i = gid0; i < Nn; i += stride) deg[i] = 1;
    for (int i = gid0; i < 32 * 256; i += stride) gpart[i] = 0.f;
    grid.sync();

    // phase 2: histogram of dst
    for (int e = gid0; e < Ee; e += stride) atomicAdd(&deg[dstv[e]], 1);
    grid.sync();

    // phase 3: per-256-chunk exclusive scan (blocks 0..NB_-1)
    if (blockIdx.x < NB_) {
        int gid = blockIdx.x * 256 + tid;
        int lane = tid & 63;
        int v = (gid < Nn) ? deg[gid] : 0;
        int x = v;
        #pragma unroll
        for (int off = 1; off < 64; off <<= 1) {
            int y = __shfl_up(x, off, 64);
            if (lane >= off) x += y;
        }
        __shared__ int wsum[4];
        if (lane == 63) wsum[tid >> 6] = x;
        __syncthreads();
        int wadd = 0;
        for (int w = 0; w < (tid >> 6); ++w) wadd += wsum[w];
        int incl = x + wadd;
        if (gid < Nn) row_start[gid] = incl - v;
        if (tid == 255) bsum[blockIdx.x] = incl;
    }
    grid.sync();

    // phase 4: single-wave scan over NB_ block sums
    if (blockIdx.x == 0 && tid < 64) {
        int lane = tid;
        int carry = 0;
        for (int base = 0; base < NB_; base += 64) {
            int i = base + lane;
            int v = (i < NB_) ? bsum[i] : 0;
            int x = v;
            #pragma unroll
            for (int off = 1; off < 64; off <<= 1) {
                int y = __shfl_up(x, off, 64);
                if (lane >= off) x += y;
            }
            if (i < NB_) boff[i] = carry + x - v;
            carry += __shfl(x, 63, 64);
        }
        if (lane == 0) boff[NB_] = carry;
    }
    grid.sync();

    // phase 5: add block offsets -> row_start + cursor
    for (int i = gid0; i < Nn; i += stride) {
        int v = row_start[i] + boff[i >> 8];
        row_start[i] = v;
        cursor[i] = v;
    }
    if (gid0 == 0) row_start[Nn] = boff[NB_];
    grid.sync();

    // phase 6: scatter (edges + self-loops)
    for (int e = gid0; e < Ee + Nn; e += stride) {
        if (e < Ee) {
            int d = dstv[e];
            int pos = atomicAdd(&cursor[d], 1);
            colx[pos] = srcv[e];
        } else {
            int node = e - Ee;
            int pos = atomicAdd(&cursor[node], 1);
            colx[pos] = node;
        }
    }
}

// ---------------- prep: weight transpose-split (coalesced) + x split -------
// blocks 0..63: 64x64 tile of one of the 4 weight matrices via LDS transpose.
// blocks 64.. : fp32 x -> hi/lo bf16 split, 4 elems/thread.

__global__ __launch_bounds__(256) void prep(const float* __restrict__ x,
                                            const float* __restrict__ Wl1,
                                            const float* __restrict__ Wr1,
                                            const float* __restrict__ Wl2,
                                            const float* __restrict__ Wr2,
                                            short* __restrict__ Ah,
                                            short* __restrict__ Al,
                                            short* __restrict__ WhT1,
                                            short* __restrict__ WlT1,
                                            short* __restrict__ WhT2,
                                            short* __restrict__ WlT2,
                                            int n4) {
    __shared__ float T[64][65];
    int b = blockIdx.x, tid = threadIdx.x;
    if (b < 64) {
        int m  = b >> 4;           // matrix 0..3
        int tr = (b >> 2) & 3;     // k-tile
        int tc = b & 3;            // n-tile
        const float* W = (m == 0) ? Wl1 : (m == 1) ? Wr1 : (m == 2) ? Wl2 : Wr2;
        short* Wh = (m < 2) ? WhT1 : WhT2;
        short* Wl = (m < 2) ? WlT1 : WlT2;
        int colofs = (m & 1) * 256;
        int lr = tid >> 4;           // 0..15
        int lq = (tid & 15) * 4;
        #pragma unroll
        for (int it = 0; it < 4; ++it) {
            int r = it * 16 + lr;    // k within tile
            float4 v = *(const float4*)&W[(size_t)(tr * 64 + r) * 256 + tc * 64 + lq];
            T[r][lq + 0] = v.x; T[r][lq + 1] = v.y;
            T[r][lq + 2] = v.z; T[r][lq + 3] = v.w;
        }
        __syncthreads();
        #pragma unroll
        for (int it = 0; it < 4; ++it) {
            int cl = it * 16 + lr;   // col within tile
            int kl = (tid & 15) * 4; // k base within tile
            short4 h, l;
            split1(T[kl + 0][cl], h.x, l.x);
            split1(T[kl + 1][cl], h.y, l.y);
            split1(T[kl + 2][cl], h.z, l.z);
            split1(T[kl + 3][cl], h.w, l.w);
            size_t o = (size_t)(colofs + tc * 64 + cl) * 256 + tr * 64 + kl;
            *(short4*)&Wh[o] = h;
            *(short4*)&Wl[o] = l;
        }
    } else {
        int i = (b - 64) * 256 + tid;
        if (i < n4) {
            float4 v = ((const float4*)x)[i];
            short4 h, l;
            split1(v.x, h.x, l.x);
            split1(v.y, h.y, l.y);
            split1(v.z, h.z, l.z);
            split1(v.w, h.w, l.w);
            ((short4*)Ah)[i] = h;
            ((short4*)Al)[i] = l;
        }
    }
}

// ---------------- bf16x3 MFMA fused GEMM, B staged once / 2 row-tiles ------
// [XL | XR] = A @ [Wl | Wr],  C = Ah*Wh + Al*Wh + Ah*Wl (bf16x3 split).
// Same fragment/swizzle/epilogue structure as round 4, plus:
//  - each block stages its 64 KB B-panel ONCE and processes TWO row-tiles
//    (rowt = j and j+79) -> staging traffic and barrier count halved, and
//    tile-0's stores drain under tile-1's compute.
//  - grid 632 = 8 colg x 79; XCD remap keeps colg-siblings on one XCD.

__global__ __launch_bounds__(256, 4) void mfma_gemm(const short* __restrict__ Ah,
                                                    const short* __restrict__ Al,
                                                    const short* __restrict__ WhT,
                                                    const short* __restrict__ WlT,
                                                    unsigned short* __restrict__ XLh,
                                                    float* __restrict__ XR) {
    __shared__ short BsH[64 * 256];
    __shared__ short BsL[64 * 256];

    int tid = threadIdx.x;
    int wave = tid >> 6, lane = tid & 63;
    int quad = lane >> 4, lc = lane & 15;

    int v = blockIdx.x;                 // 0..631
    int p = (v & 7) * 79 + (v >> 3);
    int j = p >> 3;                     // 0..78
    int colg = p & 7;                   // 64-col group of [Wl|Wr]
    int cbase = (colg * 64) & 255;

    // ---- stage B (hi+lo) once: swizzled source, linear LDS dest ----
    {
        int cl0 = wave * 2 + (lane >> 5);          // col_local base (0..7)
        int kcs = (lane & 31) ^ (cl0 & 7);         // pre-swizzled source chunk
        const short* srcH = WhT + (size_t)(colg * 64 + cl0) * HC + kcs * 8;
        const short* srcL = WlT + (size_t)(colg * 64 + cl0) * HC + kcs * 8;
        short* dstH = &BsH[wave * 512];
        short* dstL = &BsL[wave * 512];
        #pragma unroll
        for (int r = 0; r < 8; ++r) {
            async16(srcH + (size_t)r * 8 * HC, dstH + r * 2048);
            async16(srcL + (size_t)r * 8 * HC, dstL + r * 2048);
        }
    }
    __syncthreads();   // drains staging loads -- only barrier

    #pragma unroll
    for (int tt = 0; tt < 2; ++tt) {
        int rowt = j + tt * 79;
        if (rowt > 156) break;          // j==78 has no second tile
        int bm = rowt * 128;

        int row0 = bm + wave * 32 + lc;
        int row1 = row0 + 16;
        int ca0 = (row0 < Nn) ? row0 : (Nn - 1);
        int ca1 = (row1 < Nn) ? row1 : (Nn - 1);
        const short* pa0h = Ah + (size_t)ca0 * HC + quad * 8;
        const short* pa1h = Ah + (size_t)ca1 * HC + quad * 8;
        const short* pa0l = Al + (size_t)ca0 * HC + quad * 8;
        const short* pa1l = Al + (size_t)ca1 * HC + quad * 8;

        f32x4 acc[2][4] = {};
        #pragma unroll
        for (int c = 0; c < 8; ++c) {
            int k0 = c * 32;
            frag16 a0h = *(const frag16*)(pa0h + k0);
            frag16 a1h = *(const frag16*)(pa1h + k0);
            frag16 a0l = *(const frag16*)(pa0l + k0);
            frag16 a1l = *(const frag16*)(pa1l + k0);
            int sw = ((c * 4 + quad) ^ (lc & 7)) * 8;   // swizzled k-chunk
            frag16 bh0 = *(const frag16*)&BsH[(0 * 16 + lc) * HC + sw];
            frag16 bh1 = *(const frag16*)&BsH[(1 * 16 + lc) * HC + sw];
            frag16 bh2 = *(const frag16*)&BsH[(2 * 16 + lc) * HC + sw];
            frag16 bh3 = *(const frag16*)&BsH[(3 * 16 + lc) * HC + sw];
            frag16 bl0 = *(const frag16*)&BsL[(0 * 16 + lc) * HC + sw];
            frag16 bl1 = *(const frag16*)&BsL[(1 * 16 + lc) * HC + sw];
            frag16 bl2 = *(const frag16*)&BsL[(2 * 16 + lc) * HC + sw];
            frag16 bl3 = *(const frag16*)&BsL[(3 * 16 + lc) * HC + sw];
            // pass 1: Ah*Wh (8 independent MFMAs)
            acc[0][0] = __builtin_amdgcn_mfma_f32_16x16x32_bf16(bh0, a0h, acc[0][0], 0, 0, 0);
            acc[1][0] = __builtin_amdgcn_mfma_f32_16x16x32_bf16(bh0, a1h, acc[1][0], 0, 0, 0);
            acc[0][1] = __builtin_amdgcn_mfma_f32_16x16x32_bf16(bh1, a0h, acc[0][1], 0, 0, 0);
            acc[1][1] = __builtin_amdgcn_mfma_f32_16x16x32_bf16(bh1, a1h, acc[1][1], 0, 0, 0);
            acc[0][2] = __builtin_amdgcn_mfma_f32_16x16x32_bf16(bh2, a0h, acc[0][2], 0, 0, 0);
            acc[1][2] = __builtin_amdgcn_mfma_f32_16x16x32_bf16(bh2, a1h, acc[1][2], 0, 0, 0);
            acc[0][3] = __builtin_amdgcn_mfma_f32_16x16x32_bf16(bh3, a0h, acc[0][3], 0, 0, 0);
            acc[1][3] = __builtin_amdgcn_mfma_f32_16x16x32_bf16(bh3, a1h, acc[1][3], 0, 0, 0);
            // pass 2: Al*Wh
            acc[0][0] = __builtin_amdgcn_mfma_f32_16x16x32_bf16(bh0, a0l, acc[0][0], 0, 0, 0);
            acc[1][0] = __builtin_amdgcn_mfma_f32_16x16x32_bf16(bh0, a1l, acc[1][0], 0, 0, 0);
            acc[0][1] = __builtin_amdgcn_mfma_f32_16x16x32_bf16(bh1, a0l, acc[0][1], 0, 0, 0);
            acc[1][1] = __builtin_amdgcn_mfma_f32_16x16x32_bf16(bh1, a1l, acc[1][1], 0, 0, 0);
            acc[0][2] = __builtin_amdgcn_mfma_f32_16x16x32_bf16(bh2, a0l, acc[0][2], 0, 0, 0);
            acc[1][2] = __builtin_amdgcn_mfma_f32_16x16x32_bf16(bh2, a1l, acc[1][2], 0, 0, 0);
            acc[0][3] = __builtin_amdgcn_mfma_f32_16x16x32_bf16(bh3, a0l, acc[0][3], 0, 0, 0);
            acc[1][3] = __builtin_amdgcn_mfma_f32_16x16x32_bf16(bh3, a1l, acc[1][3], 0, 0, 0);
            // pass 3: Ah*Wl
            acc[0][0] = __builtin_amdgcn_mfma_f32_16x16x32_bf16(bl0, a0h, acc[0][0], 0, 0, 0);
            acc[1][0] = __builtin_amdgcn_mfma_f32_16x16x32_bf16(bl0, a1h, acc[1][0], 0, 0, 0);
            acc[0][1] = __builtin_amdgcn_mfma_f32_16x16x32_bf16(bl1, a0h, acc[0][1], 0, 0, 0);
            acc[1][1] = __builtin_amdgcn_mfma_f32_16x16x32_bf16(bl1, a1h, acc[1][1], 0, 0, 0);
            acc[0][2] = __builtin_amdgcn_mfma_f32_16x16x32_bf16(bl2, a0h, acc[0][2], 0, 0, 0);
            acc[1][2] = __builtin_amdgcn_mfma_f32_16x16x32_bf16(bl2, a1h, acc[1][2], 0, 0, 0);
            acc[0][3] = __builtin_amdgcn_mfma_f32_16x16x32_bf16(bl3, a0h, acc[0][3], 0, 0, 0);
            acc[1][3] = __builtin_amdgcn_mfma_f32_16x16x32_bf16(bl3, a1h, acc[1][3], 0, 0, 0);
        }

        // transposed C-layout epilogue: lane (quad,lc) holds row (..+lc),
        // cols (cbase + t*16 + quad*4 .. +3) -> vector stores.
        #pragma unroll
        for (int mt = 0; mt < 2; ++mt) {
            int rw = bm + wave * 32 + mt * 16 + lc;
            if (rw >= Nn) continue;
            #pragma unroll
            for (int t = 0; t < 4; ++t) {
                int col0 = cbase + t * 16 + quad * 4;
                if (colg < 4) {
                    ushort4 o;
                    o.x = bf16rn(acc[mt][t][0]);
                    o.y = bf16rn(acc[mt][t][1]);
                    o.z = bf16rn(acc[mt][t][2]);
                    o.w = bf16rn(acc[mt][t][3]);
                    *(ushort4*)&XLh[(size_t)rw * HC + col0] = o;
                } else {
                    *(f32x4*)&XR[(size_t)rw * HC + col0] = acc[mt][t];
                }
            }
        }
    }
}

// ---------------- GATv2 edge phase ----------------
// One wave per node (4 nodes/block). Lane holds 4 channels; head h = lanes
// 16h..16h+15. XL gathered in bf16 (8 B/lane); XR/bias fp32.
// No-max softmax (scores bounded << 88); leaky(t)=0.6t+0.4|t|.
// mode 1: write bf16 hi/lo split of relu(h) for next layer's GEMM.
// mode 0: fused pooling -- block-reduce the 4 nodes' outputs and atomicAdd
//         into 32-sliced gpart (no Hb round-trip, no colsum dispatch).

__device__ __forceinline__ float edge_score(const float4 v, const float4 xr,
                                            const float4 a06, const float4 a04) {
    float tx = v.x + xr.x, ty = v.y + xr.y, tz = v.z + xr.z, tw = v.w + xr.w;
    float p = a06.x * tx + a04.x * fabsf(tx);
    p += a06.y * ty + a04.y * fabsf(ty);
    p += a06.z * tz + a04.z * fabsf(tz);
    p += a06.w * tw + a04.w * fabsf(tw);
    p += __shfl_xor(p, 1, 64);
    p += __shfl_xor(p, 2, 64);
    p += __shfl_xor(p, 4, 64);
    p += __shfl_xor(p, 8, 64);             // per-head score in its 16 lanes
    return p;
}

__global__ __launch_bounds__(256) void gat_kernel(const ushort4* __restrict__ XL4,
                                                  const float4* __restrict__ XR4,
                                                  const int* __restrict__ row_start,
                                                  const int* __restrict__ colx,
                                                  const float4* __restrict__ att4,
                                                  const float4* __restrict__ bias4,
                                                  float* __restrict__ gpart,
                                                  short4* __restrict__ Ahi,
                                                  short4* __restrict__ Alo,
                                                  int mode) {
    __shared__ float4 sred[4][64];
    int wave = threadIdx.x >> 6, lane = threadIdx.x & 63;
    int node = blockIdx.x * 4 + wave;          // grid = Nn/4 exactly
    float4 xr = XR4[(size_t)node * 64 + lane];
    float4 a  = att4[lane];
    float4 a06 = make_float4(a.x * 0.6f, a.y * 0.6f, a.z * 0.6f, a.w * 0.6f);
    float4 a04 = make_float4(a.x * 0.4f, a.y * 0.4f, a.z * 0.4f, a.w * 0.4f);
    int e0 = __builtin_amdgcn_readfirstlane(row_start[node]);
    int e1 = __builtin_amdgcn_readfirstlane(row_start[node + 1]);
    float l0 = 0.f, l1 = 0.f;
    float4 acc0 = make_float4(0.f, 0.f, 0.f, 0.f);
    float4 acc1 = make_float4(0.f, 0.f, 0.f, 0.f);
    int npairs = (e1 - e0) >> 1;
    int e = e0;
    int s0 = 0, s1 = 0;
    if (npairs > 0) { s0 = colx[e]; s1 = colx[e + 1]; }    // scalar loads
    for (int pp = 0; pp < npairs; ++pp) {
        int en = e + 2;
        int i0 = (en     < e1) ? en     : (e1 - 1);
        int i1 = (en + 1 < e1) ? en + 1 : (e1 - 1);
        int ns0 = colx[i0];                   // prefetch next pair (scalar)
        int ns1 = colx[i1];
        ushort4 u0 = XL4[(size_t)s0 * 64 + lane];
        ushort4 u1 = XL4[(size_t)s1 * 64 + lane];
        float4 v0 = bf4_to_f4(u0);
        float4 v1 = bf4_to_f4(u1);
        float pe0 = __expf(edge_score(v0, xr, a06, a04));
        float pe1 = __expf(edge_score(v1, xr, a06, a04));
        l0 += pe0; l1 += pe1;
        acc0.x += pe0 * v0.x; acc0.y += pe0 * v0.y;
        acc0.z += pe0 * v0.z; acc0.w += pe0 * v0.w;
        acc1.x += pe1 * v1.x; acc1.y += pe1 * v1.y;
        acc1.z += pe1 * v1.z; acc1.w += pe1 * v1.w;
        s0 = ns0; s1 = ns1; e = en;
    }
    if (e < e1) {                              // odd tail edge
        int st = colx[e];
        float4 v0 = bf4_to_f4(XL4[(size_t)st * 64 + lane]);
        float pe0 = __expf(edge_score(v0, xr, a06, a04));
        l0 += pe0;
        acc0.x += pe0 * v0.x; acc0.y += pe0 * v0.y;
        acc0.z += pe0 * v0.z; acc0.w += pe0 * v0.w;
    }
    float rl = 1.f / (l0 + l1);
    float4 b = bias4[lane];
    float4 o = make_float4(fmaxf((acc0.x + acc1.x) * rl + b.x, 0.f),
                           fmaxf((acc0.y + acc1.y) * rl + b.y, 0.f),
                           fmaxf((acc0.z + acc1.z) * rl + b.z, 0.f),
                           fmaxf((acc0.w + acc1.w) * rl + b.w, 0.f));
    if (mode) {
        short4 h4, l4;
        split1(o.x, h4.x, l4.x);
        split1(o.y, h4.y, l4.y);
        split1(o.z, h4.z, l4.z);
        split1(o.w, h4.w, l4.w);
        size_t oidx = (size_t)node * 64 + lane;
        Ahi[oidx] = h4;
        Alo[oidx] = l4;
    } else {
        sred[wave][lane] = o;
        __syncthreads();
        if (threadIdx.x < 64) {
            int l = threadIdx.x;
            float4 s = sred[0][l];
            float4 s1v = sred[1][l], s2v = sred[2][l], s3v = sred[3][l];
            s.x += s1v.x + s2v.x + s3v.x;
            s.y += s1v.y + s2v.y + s3v.y;
            s.z += s1v.z + s2v.z + s3v.z;
            s.w += s1v.w + s2v.w + s3v.w;
            float* gp = gpart + (blockIdx.x & 31) * 256 + l * 4;
            atomicAdd(gp + 0, s.x);
            atomicAdd(gp + 1, s.y);
            atomicAdd(gp + 2, s.z);
            atomicAdd(gp + 3, s.w);
        }
    }
}

// ---------------- FC (sums 32 pooling slices) ----------------

__global__ __launch_bounds__(256) void fc_kernel(const float* __restrict__ gpart,
                                                 const float* __restrict__ Wfc,
                                                 const float* __restrict__ bfc,
                                                 float* __restrict__ out, float invN) {
    int t = threadIdx.x;
    float s = 0.f;
    #pragma unroll
    for (int k = 0; k < 32; ++k) s += gpart[k * 256 + t];
    float gv = s * invN;
    float p0 = gv * Wfc[2 * t];
    float p1 = gv * Wfc[2 * t + 1];
    #pragma unroll
    for (int off = 32; off > 0; off >>= 1) {
        p0 += __shfl_xor(p0, off, 64);
        p1 += __shfl_xor(p1, off, 64);
    }
    __shared__ float s0[4], s1[4];
    if ((t & 63) == 0) { s0[t >> 6] = p0; s1[t >> 6] = p1; }
    __syncthreads();
    if (t == 0) {
        out[0] = s0[0] + s0[1] + s0[2] + s0[3] + bfc[0];
        out[1] = s1[0] + s1[1] + s1[2] + s1[3] + bfc[1];
    }
}

// ---------------- launch ----------------

extern "C" void kernel_launch(void* const* d_in, const int* in_sizes, int n_in,
                              void* d_out, int out_size, void* d_ws, size_t ws_size,
                              hipStream_t stream) {
    const float* x    = (const float*)d_in[0];
    const int*   eidx = (const int*)d_in[1];   // (2,E) row-major: [src | dst]
    const float* Wl1  = (const float*)d_in[2];
    const float* Wr1  = (const float*)d_in[3];
    const float* att1 = (const float*)d_in[4];
    const float* b1   = (const float*)d_in[5];
    const float* Wl2  = (const float*)d_in[6];
    const float* Wr2  = (const float*)d_in[7];
    const float* att2 = (const float*)d_in[8];
    const float* b2   = (const float*)d_in[9];
    const float* Wfc  = (const float*)d_in[10];
    const float* bfc  = (const float*)d_in[11];
    float* out = (float*)d_out;

    const int* srcv = eidx;
    const int* dstv = eidx + Ee;

    // workspace layout
    size_t NHC = (size_t)Nn * HC;
    float* XR = (float*)d_ws;
    float* gpart = XR + NHC;                   // 32*256 pooling slices
    unsigned short* XLh = (unsigned short*)(gpart + 32 * 256);
    short* Ah   = (short*)(XLh + NHC);
    short* Al   = Ah + NHC;
    short* WhT1 = Al + NHC;                    // 512*256 concat [Wl|Wr]^T per layer
    short* WlT1 = WhT1 + 512 * 256;
    short* WhT2 = WlT1 + 512 * 256;
    short* WlT2 = WhT2 + 512 * 256;
    int* deg       = (int*)(WlT2 + 512 * 256);
    int* row_start = deg + Nn;
    int* cursor    = row_start + (Nn + 1);
    int* colx      = cursor + Nn;              // Ee + Nn entries
    int* bsum      = colx + (Ee + Nn);
    int* boff      = bsum + 128;               // NB_+1 entries

    const int N4 = (int)(NHC / 4);             // 320000

    // 1) weight transpose-split + x split (one dispatch)
    prep<<<64 + (N4 + 255) / 256, 256, 0, stream>>>(x, Wl1, Wr1, Wl2, Wr2,
                                                    Ah, Al, WhT1, WlT1, WhT2, WlT2, N4);

    // 2) CSR build (single cooperative dispatch, 6 phases)
    {
        void* cargs[] = {(void*)&dstv, (void*)&srcv, (void*)&deg, (void*)&row_start,
                         (void*)&cursor, (void*)&colx, (void*)&bsum, (void*)&boff,
                         (void*)&gpart};
        hipLaunchCooperativeKernel((const void*)csr_coop, dim3(1024), dim3(256),
                                   cargs, 0, stream);
    }

    const int GB = 8 * 79;                     // 632 blocks, %8 == 0

    // 3) layer 1
    mfma_gemm<<<GB, 256, 0, stream>>>(Ah, Al, WhT1, WlT1, XLh, XR);
    gat_kernel<<<Nn / 4, 256, 0, stream>>>((const ushort4*)XLh, (const float4*)XR,
                                           row_start, colx, (const float4*)att1,
                                           (const float4*)b1, gpart,
                                           (short4*)Ah, (short4*)Al, 1);

    // 4) layer 2 (gat fuses pooling into gpart)
    mfma_gemm<<<GB, 256, 0, stream>>>(Ah, Al, WhT2, WlT2, XLh, XR);
    gat_kernel<<<Nn / 4, 256, 0, stream>>>((const ushort4*)XLh, (const float4*)XR,
                                           row_start, colx, (const float4*)att2,
                                           (const float4*)b2, gpart,
                                           (short4*)Ah, (short4*)Al, 0);

    // 5) FC
    fc_kernel<<<1, 256, 0, stream>>>(gpart, Wfc, bfc, out, 1.0f / Nn);
}

// Round 6
// 262.952 us; speedup vs baseline: 3.0526x; 3.0526x over previous
//
#include <hip/hip_runtime.h>
#include <hip/hip_bf16.h>
#include <math.h>

#define Nn 20000
#define Ee 320000
#define INF_ 256
#define Hh 4
#define Cc 64
#define HC 256
#define NB_ 79
#define NEG_SLOPE 0.2f

using frag16 = __attribute__((ext_vector_type(8))) short;   // 8 bf16 (4 VGPRs)
using f32x4  = __attribute__((ext_vector_type(4))) float;

// async global->LDS 16B per lane; LDS dest = wave-uniform base + lane*16
__device__ __forceinline__ void async16(const void* g, void* l) {
    __builtin_amdgcn_global_load_lds(
        (const __attribute__((address_space(1))) unsigned int*)g,
        (__attribute__((address_space(3))) unsigned int*)l,
        16, 0, 0);
}

// ---------------- CSR build (multi-dispatch; cooperative grid.sync was a
// 572 us disaster in round 5 -- reverted) ----------------

__global__ void init_deg(int* deg, float* gpart, int n) {
    int i = blockIdx.x * blockDim.x + threadIdx.x;
    if (i < n) deg[i] = 1;  // self-loop pre-counted
    if (i < 32 * 256) gpart[i] = 0.f;
}

__global__ void hist_kernel(const int* __restrict__ dst, int ne, int* deg) {
    int e = blockIdx.x * blockDim.x + threadIdx.x;
    if (e < ne) atomicAdd(&deg[dst[e]], 1);
}

// hierarchical scan, phase 1: per-block (256 elems) exclusive scan + block sum
__global__ __launch_bounds__(256) void scan1(const int* __restrict__ deg,
                                             int* __restrict__ excl,
                                             int* __restrict__ bsum, int n) {
    int tid = threadIdx.x;
    int gid = blockIdx.x * 256 + tid;
    int lane = tid & 63;
    int v = (gid < n) ? deg[gid] : 0;
    int x = v;
    #pragma unroll
    for (int off = 1; off < 64; off <<= 1) {
        int y = __shfl_up(x, off, 64);
        if (lane >= off) x += y;
    }
    __shared__ int wsum[4];
    if (lane == 63) wsum[tid >> 6] = x;
    __syncthreads();
    int wadd = 0;
    for (int w = 0; w < (tid >> 6); ++w) wadd += wsum[w];
    int incl = x + wadd;
    if (gid < n) excl[gid] = incl - v;
    if (tid == 255) bsum[blockIdx.x] = incl;
}

// phase 2: single-wave scan over block sums (nb ~ 79 -> 2 iters)
__global__ void scan2(const int* __restrict__ bsum, int* __restrict__ boff, int nb) {
    int lane = threadIdx.x;
    int carry = 0;
    for (int base = 0; base < nb; base += 64) {
        int i = base + lane;
        int v = (i < nb) ? bsum[i] : 0;
        int x = v;
        #pragma unroll
        for (int off = 1; off < 64; off <<= 1) {
            int y = __shfl_up(x, off, 64);
            if (lane >= off) x += y;
        }
        if (i < nb) boff[i] = carry + x - v;
        carry += __shfl(x, 63, 64);
    }
    if (lane == 0) boff[nb] = carry;
}

// phase 3: add block offsets, produce row_start + cursor (+ total at [n])
__global__ void scan_add(int* __restrict__ row_start, int* __restrict__ cursor,
                         const int* __restrict__ boff, int n, int nb) {
    int gid = blockIdx.x * blockDim.x + threadIdx.x;
    if (gid < n) {
        int v = row_start[gid] + boff[gid >> 8];
        row_start[gid] = v;
        cursor[gid] = v;
    }
    if (gid == n) row_start[n] = boff[nb];
}

__global__ void scatter_kernel(const int* __restrict__ src, const int* __restrict__ dst,
                               int ne, int n, int* cursor, int* colx) {
    int e = blockIdx.x * blockDim.x + threadIdx.x;
    if (e < ne) {
        int d = dst[e];
        int pos = atomicAdd(&cursor[d], 1);
        colx[pos] = src[e];
    } else if (e < ne + n) {
        int node = e - ne;
        int pos = atomicAdd(&cursor[node], 1);
        colx[pos] = node;  // self-loop
    }
}

// ---------------- bf16 split-precision helpers ----------------

__device__ inline unsigned short bf16rn(float f) {
    unsigned u = __float_as_uint(f);
    unsigned r = (u + 0x7FFFu + ((u >> 16) & 1u)) >> 16;   // RTNE
    return (unsigned short)r;
}

__device__ inline void split1(float v, short& h, short& l) {
    unsigned short hh = bf16rn(v);
    float back = __uint_as_float(((unsigned)hh) << 16);
    unsigned short ll = bf16rn(v - back);
    h = (short)hh; l = (short)ll;
}

__device__ __forceinline__ float4 bf4_to_f4(ushort4 u) {
    return make_float4(__uint_as_float((unsigned)u.x << 16),
                       __uint_as_float((unsigned)u.y << 16),
                       __uint_as_float((unsigned)u.z << 16),
                       __uint_as_float((unsigned)u.w << 16));
}

// ---------------- prep: weight transpose-split (coalesced) + x split -------
// blocks 0..63: 64x64 tile of one of the 4 weight matrices via LDS transpose.
// blocks 64.. : fp32 x -> hi/lo bf16 split, 4 elems/thread.

__global__ __launch_bounds__(256) void prep(const float* __restrict__ x,
                                            const float* __restrict__ Wl1,
                                            const float* __restrict__ Wr1,
                                            const float* __restrict__ Wl2,
                                            const float* __restrict__ Wr2,
                                            short* __restrict__ Ah,
                                            short* __restrict__ Al,
                                            short* __restrict__ WhT1,
                                            short* __restrict__ WlT1,
                                            short* __restrict__ WhT2,
                                            short* __restrict__ WlT2,
                                            int n4) {
    __shared__ float T[64][65];
    int b = blockIdx.x, tid = threadIdx.x;
    if (b < 64) {
        int m  = b >> 4;           // matrix 0..3
        int tr = (b >> 2) & 3;     // k-tile
        int tc = b & 3;            // n-tile
        const float* W = (m == 0) ? Wl1 : (m == 1) ? Wr1 : (m == 2) ? Wl2 : Wr2;
        short* Wh = (m < 2) ? WhT1 : WhT2;
        short* Wl = (m < 2) ? WlT1 : WlT2;
        int colofs = (m & 1) * 256;
        int lr = tid >> 4;           // 0..15
        int lq = (tid & 15) * 4;
        #pragma unroll
        for (int it = 0; it < 4; ++it) {
            int r = it * 16 + lr;    // k within tile
            float4 v = *(const float4*)&W[(size_t)(tr * 64 + r) * 256 + tc * 64 + lq];
            T[r][lq + 0] = v.x; T[r][lq + 1] = v.y;
            T[r][lq + 2] = v.z; T[r][lq + 3] = v.w;
        }
        __syncthreads();
        #pragma unroll
        for (int it = 0; it < 4; ++it) {
            int cl = it * 16 + lr;   // col within tile
            int kl = (tid & 15) * 4; // k base within tile
            short4 h, l;
            split1(T[kl + 0][cl], h.x, l.x);
            split1(T[kl + 1][cl], h.y, l.y);
            split1(T[kl + 2][cl], h.z, l.z);
            split1(T[kl + 3][cl], h.w, l.w);
            size_t o = (size_t)(colofs + tc * 64 + cl) * 256 + tr * 64 + kl;
            *(short4*)&Wh[o] = h;
            *(short4*)&Wl[o] = l;
        }
    } else {
        int i = (b - 64) * 256 + tid;
        if (i < n4) {
            float4 v = ((const float4*)x)[i];
            short4 h, l;
            split1(v.x, h.x, l.x);
            split1(v.y, h.y, l.y);
            split1(v.z, h.z, l.z);
            split1(v.w, h.w, l.w);
            ((short4*)Ah)[i] = h;
            ((short4*)Al)[i] = l;
        }
    }
}

// ---------------- bf16x3 MFMA fused GEMM, B staged once / 2 row-tiles ------
// [XL | XR] = A @ [Wl | Wr],  C = Ah*Wh + Al*Wh + Ah*Wl (bf16x3 split).
//  - 64 KB B-panel staged once per block (swizzled source, linear LDS dest,
//    ONE barrier), then TWO row-tiles (rowt = j, j+79) -> stage amortized.
//  - A fragments loaded direct global->VGPR, K-loop fully unrolled.
//  - Swapped-operand MFMA -> transposed tile; vector epilogue stores.
//  - 3 passes of 8 independent MFMAs; acc reuse distance 8.
//  - XCD remap keeps colg-siblings of one j on the same XCD.

__global__ __launch_bounds__(256, 4) void mfma_gemm(const short* __restrict__ Ah,
                                                    const short* __restrict__ Al,
                                                    const short* __restrict__ WhT,
                                                    const short* __restrict__ WlT,
                                                    unsigned short* __restrict__ XLh,
                                                    float* __restrict__ XR) {
    __shared__ short BsH[64 * 256];
    __shared__ short BsL[64 * 256];

    int tid = threadIdx.x;
    int wave = tid >> 6, lane = tid & 63;
    int quad = lane >> 4, lc = lane & 15;

    int v = blockIdx.x;                 // 0..631
    int p = (v & 7) * 79 + (v >> 3);
    int j = p >> 3;                     // 0..78
    int colg = p & 7;                   // 64-col group of [Wl|Wr]
    int cbase = (colg * 64) & 255;

    // ---- stage B (hi+lo) once: swizzled source, linear LDS dest ----
    {
        int cl0 = wave * 2 + (lane >> 5);          // col_local base (0..7)
        int kcs = (lane & 31) ^ (cl0 & 7);         // pre-swizzled source chunk
        const short* srcH = WhT + (size_t)(colg * 64 + cl0) * HC + kcs * 8;
        const short* srcL = WlT + (size_t)(colg * 64 + cl0) * HC + kcs * 8;
        short* dstH = &BsH[wave * 512];
        short* dstL = &BsL[wave * 512];
        #pragma unroll
        for (int r = 0; r < 8; ++r) {
            async16(srcH + (size_t)r * 8 * HC, dstH + r * 2048);
            async16(srcL + (size_t)r * 8 * HC, dstL + r * 2048);
        }
    }
    __syncthreads();   // drains staging loads -- only barrier

    #pragma unroll
    for (int tt = 0; tt < 2; ++tt) {
        int rowt = j + tt * 79;
        if (rowt > 156) break;          // j==78 has no second tile
        int bm = rowt * 128;

        int row0 = bm + wave * 32 + lc;
        int row1 = row0 + 16;
        int ca0 = (row0 < Nn) ? row0 : (Nn - 1);
        int ca1 = (row1 < Nn) ? row1 : (Nn - 1);
        const short* pa0h = Ah + (size_t)ca0 * HC + quad * 8;
        const short* pa1h = Ah + (size_t)ca1 * HC + quad * 8;
        const short* pa0l = Al + (size_t)ca0 * HC + quad * 8;
        const short* pa1l = Al + (size_t)ca1 * HC + quad * 8;

        f32x4 acc[2][4] = {};
        #pragma unroll
        for (int c = 0; c < 8; ++c) {
            int k0 = c * 32;
            frag16 a0h = *(const frag16*)(pa0h + k0);
            frag16 a1h = *(const frag16*)(pa1h + k0);
            frag16 a0l = *(const frag16*)(pa0l + k0);
            frag16 a1l = *(const frag16*)(pa1l + k0);
            int sw = ((c * 4 + quad) ^ (lc & 7)) * 8;   // swizzled k-chunk
            frag16 bh0 = *(const frag16*)&BsH[(0 * 16 + lc) * HC + sw];
            frag16 bh1 = *(const frag16*)&BsH[(1 * 16 + lc) * HC + sw];
            frag16 bh2 = *(const frag16*)&BsH[(2 * 16 + lc) * HC + sw];
            frag16 bh3 = *(const frag16*)&BsH[(3 * 16 + lc) * HC + sw];
            frag16 bl0 = *(const frag16*)&BsL[(0 * 16 + lc) * HC + sw];
            frag16 bl1 = *(const frag16*)&BsL[(1 * 16 + lc) * HC + sw];
            frag16 bl2 = *(const frag16*)&BsL[(2 * 16 + lc) * HC + sw];
            frag16 bl3 = *(const frag16*)&BsL[(3 * 16 + lc) * HC + sw];
            // pass 1: Ah*Wh (8 independent MFMAs)
            acc[0][0] = __builtin_amdgcn_mfma_f32_16x16x32_bf16(bh0, a0h, acc[0][0], 0, 0, 0);
            acc[1][0] = __builtin_amdgcn_mfma_f32_16x16x32_bf16(bh0, a1h, acc[1][0], 0, 0, 0);
            acc[0][1] = __builtin_amdgcn_mfma_f32_16x16x32_bf16(bh1, a0h, acc[0][1], 0, 0, 0);
            acc[1][1] = __builtin_amdgcn_mfma_f32_16x16x32_bf16(bh1, a1h, acc[1][1], 0, 0, 0);
            acc[0][2] = __builtin_amdgcn_mfma_f32_16x16x32_bf16(bh2, a0h, acc[0][2], 0, 0, 0);
            acc[1][2] = __builtin_amdgcn_mfma_f32_16x16x32_bf16(bh2, a1h, acc[1][2], 0, 0, 0);
            acc[0][3] = __builtin_amdgcn_mfma_f32_16x16x32_bf16(bh3, a0h, acc[0][3], 0, 0, 0);
            acc[1][3] = __builtin_amdgcn_mfma_f32_16x16x32_bf16(bh3, a1h, acc[1][3], 0, 0, 0);
            // pass 2: Al*Wh
            acc[0][0] = __builtin_amdgcn_mfma_f32_16x16x32_bf16(bh0, a0l, acc[0][0], 0, 0, 0);
            acc[1][0] = __builtin_amdgcn_mfma_f32_16x16x32_bf16(bh0, a1l, acc[1][0], 0, 0, 0);
            acc[0][1] = __builtin_amdgcn_mfma_f32_16x16x32_bf16(bh1, a0l, acc[0][1], 0, 0, 0);
            acc[1][1] = __builtin_amdgcn_mfma_f32_16x16x32_bf16(bh1, a1l, acc[1][1], 0, 0, 0);
            acc[0][2] = __builtin_amdgcn_mfma_f32_16x16x32_bf16(bh2, a0l, acc[0][2], 0, 0, 0);
            acc[1][2] = __builtin_amdgcn_mfma_f32_16x16x32_bf16(bh2, a1l, acc[1][2], 0, 0, 0);
            acc[0][3] = __builtin_amdgcn_mfma_f32_16x16x32_bf16(bh3, a0l, acc[0][3], 0, 0, 0);
            acc[1][3] = __builtin_amdgcn_mfma_f32_16x16x32_bf16(bh3, a1l, acc[1][3], 0, 0, 0);
            // pass 3: Ah*Wl
            acc[0][0] = __builtin_amdgcn_mfma_f32_16x16x32_bf16(bl0, a0h, acc[0][0], 0, 0, 0);
            acc[1][0] = __builtin_amdgcn_mfma_f32_16x16x32_bf16(bl0, a1h, acc[1][0], 0, 0, 0);
            acc[0][1] = __builtin_amdgcn_mfma_f32_16x16x32_bf16(bl1, a0h, acc[0][1], 0, 0, 0);
            acc[1][1] = __builtin_amdgcn_mfma_f32_16x16x32_bf16(bl1, a1h, acc[1][1], 0, 0, 0);
            acc[0][2] = __builtin_amdgcn_mfma_f32_16x16x32_bf16(bl2, a0h, acc[0][2], 0, 0, 0);
            acc[1][2] = __builtin_amdgcn_mfma_f32_16x16x32_bf16(bl2, a1h, acc[1][2], 0, 0, 0);
            acc[0][3] = __builtin_amdgcn_mfma_f32_16x16x32_bf16(bl3, a0h, acc[0][3], 0, 0, 0);
            acc[1][3] = __builtin_amdgcn_mfma_f32_16x16x32_bf16(bl3, a1h, acc[1][3], 0, 0, 0);
        }

        // transposed C-layout epilogue: lane (quad,lc) holds row (..+lc),
        // cols (cbase + t*16 + quad*4 .. +3) -> vector stores.
        #pragma unroll
        for (int mt = 0; mt < 2; ++mt) {
            int rw = bm + wave * 32 + mt * 16 + lc;
            if (rw >= Nn) continue;
            #pragma unroll
            for (int t = 0; t < 4; ++t) {
                int col0 = cbase + t * 16 + quad * 4;
                if (colg < 4) {
                    ushort4 o;
                    o.x = bf16rn(acc[mt][t][0]);
                    o.y = bf16rn(acc[mt][t][1]);
                    o.z = bf16rn(acc[mt][t][2]);
                    o.w = bf16rn(acc[mt][t][3]);
                    *(ushort4*)&XLh[(size_t)rw * HC + col0] = o;
                } else {
                    *(f32x4*)&XR[(size_t)rw * HC + col0] = acc[mt][t];
                }
            }
        }
    }
}

// ---------------- GATv2 edge phase ----------------
// One wave per node (4 nodes/block). Lane holds 4 channels; head h = lanes
// 16h..16h+15. XL gathered in bf16 (8 B/lane); XR/bias fp32.
// No-max softmax (scores bounded << 88); leaky(t)=0.6t+0.4|t|.
// mode 1: write bf16 hi/lo split of relu(h) for next layer's GEMM.
// mode 0: fused pooling -- block-reduce the 4 nodes' outputs and atomicAdd
//         into 32-sliced gpart (no Hb round-trip, no colsum dispatch).

__device__ __forceinline__ float edge_score(const float4 v, const float4 xr,
                                            const float4 a06, const float4 a04) {
    float tx = v.x + xr.x, ty = v.y + xr.y, tz = v.z + xr.z, tw = v.w + xr.w;
    float p = a06.x * tx + a04.x * fabsf(tx);
    p += a06.y * ty + a04.y * fabsf(ty);
    p += a06.z * tz + a04.z * fabsf(tz);
    p += a06.w * tw + a04.w * fabsf(tw);
    p += __shfl_xor(p, 1, 64);
    p += __shfl_xor(p, 2, 64);
    p += __shfl_xor(p, 4, 64);
    p += __shfl_xor(p, 8, 64);             // per-head score in its 16 lanes
    return p;
}

__global__ __launch_bounds__(256) void gat_kernel(const ushort4* __restrict__ XL4,
                                                  const float4* __restrict__ XR4,
                                                  const int* __restrict__ row_start,
                                                  const int* __restrict__ colx,
                                                  const float4* __restrict__ att4,
                                                  const float4* __restrict__ bias4,
                                                  float* __restrict__ gpart,
                                                  short4* __restrict__ Ahi,
                                                  short4* __restrict__ Alo,
                                                  int mode) {
    __shared__ float4 sred[4][64];
    int wave = threadIdx.x >> 6, lane = threadIdx.x & 63;
    int node = blockIdx.x * 4 + wave;          // grid = Nn/4 exactly
    float4 xr = XR4[(size_t)node * 64 + lane];
    float4 a  = att4[lane];
    float4 a06 = make_float4(a.x * 0.6f, a.y * 0.6f, a.z * 0.6f, a.w * 0.6f);
    float4 a04 = make_float4(a.x * 0.4f, a.y * 0.4f, a.z * 0.4f, a.w * 0.4f);
    int e0 = __builtin_amdgcn_readfirstlane(row_start[node]);
    int e1 = __builtin_amdgcn_readfirstlane(row_start[node + 1]);
    float l0 = 0.f, l1 = 0.f;
    float4 acc0 = make_float4(0.f, 0.f, 0.f, 0.f);
    float4 acc1 = make_float4(0.f, 0.f, 0.f, 0.f);
    int npairs = (e1 - e0) >> 1;
    int e = e0;
    int s0 = 0, s1 = 0;
    if (npairs > 0) { s0 = colx[e]; s1 = colx[e + 1]; }    // scalar loads
    for (int pp = 0; pp < npairs; ++pp) {
        int en = e + 2;
        int i0 = (en     < e1) ? en     : (e1 - 1);
        int i1 = (en + 1 < e1) ? en + 1 : (e1 - 1);
        int ns0 = colx[i0];                   // prefetch next pair (scalar)
        int ns1 = colx[i1];
        ushort4 u0 = XL4[(size_t)s0 * 64 + lane];
        ushort4 u1 = XL4[(size_t)s1 * 64 + lane];
        float4 v0 = bf4_to_f4(u0);
        float4 v1 = bf4_to_f4(u1);
        float pe0 = __expf(edge_score(v0, xr, a06, a04));
        float pe1 = __expf(edge_score(v1, xr, a06, a04));
        l0 += pe0; l1 += pe1;
        acc0.x += pe0 * v0.x; acc0.y += pe0 * v0.y;
        acc0.z += pe0 * v0.z; acc0.w += pe0 * v0.w;
        acc1.x += pe1 * v1.x; acc1.y += pe1 * v1.y;
        acc1.z += pe1 * v1.z; acc1.w += pe1 * v1.w;
        s0 = ns0; s1 = ns1; e = en;
    }
    if (e < e1) {                              // odd tail edge
        int st = colx[e];
        float4 v0 = bf4_to_f4(XL4[(size_t)st * 64 + lane]);
        float pe0 = __expf(edge_score(v0, xr, a06, a04));
        l0 += pe0;
        acc0.x += pe0 * v0.x; acc0.y += pe0 * v0.y;
        acc0.z += pe0 * v0.z; acc0.w += pe0 * v0.w;
    }
    float rl = 1.f / (l0 + l1);
    float4 b = bias4[lane];
    float4 o = make_float4(fmaxf((acc0.x + acc1.x) * rl + b.x, 0.f),
                           fmaxf((acc0.y + acc1.y) * rl + b.y, 0.f),
                           fmaxf((acc0.z + acc1.z) * rl + b.z, 0.f),
                           fmaxf((acc0.w + acc1.w) * rl + b.w, 0.f));
    if (mode) {
        short4 h4, l4;
        split1(o.x, h4.x, l4.x);
        split1(o.y, h4.y, l4.y);
        split1(o.z, h4.z, l4.z);
        split1(o.w, h4.w, l4.w);
        size_t oidx = (size_t)node * 64 + lane;
        Ahi[oidx] = h4;
        Alo[oidx] = l4;
    } else {
        sred[wave][lane] = o;
        __syncthreads();
        if (threadIdx.x < 64) {
            int l = threadIdx.x;
            float4 s = sred[0][l];
            float4 s1v = sred[1][l], s2v = sred[2][l], s3v = sred[3][l];
            s.x += s1v.x + s2v.x + s3v.x;
            s.y += s1v.y + s2v.y + s3v.y;
            s.z += s1v.z + s2v.z + s3v.z;
            s.w += s1v.w + s2v.w + s3v.w;
            float* gp = gpart + (blockIdx.x & 31) * 256 + l * 4;
            atomicAdd(gp + 0, s.x);
            atomicAdd(gp + 1, s.y);
            atomicAdd(gp + 2, s.z);
            atomicAdd(gp + 3, s.w);
        }
    }
}

// ---------------- FC (sums 32 pooling slices) ----------------

__global__ __launch_bounds__(256) void fc_kernel(const float* __restrict__ gpart,
                                                 const float* __restrict__ Wfc,
                                                 const float* __restrict__ bfc,
                                                 float* __restrict__ out, float invN) {
    int t = threadIdx.x;
    float s = 0.f;
    #pragma unroll
    for (int k = 0; k < 32; ++k) s += gpart[k * 256 + t];
    float gv = s * invN;
    float p0 = gv * Wfc[2 * t];
    float p1 = gv * Wfc[2 * t + 1];
    #pragma unroll
    for (int off = 32; off > 0; off >>= 1) {
        p0 += __shfl_xor(p0, off, 64);
        p1 += __shfl_xor(p1, off, 64);
    }
    __shared__ float s0[4], s1[4];
    if ((t & 63) == 0) { s0[t >> 6] = p0; s1[t >> 6] = p1; }
    __syncthreads();
    if (t == 0) {
        out[0] = s0[0] + s0[1] + s0[2] + s0[3] + bfc[0];
        out[1] = s1[0] + s1[1] + s1[2] + s1[3] + bfc[1];
    }
}

// ---------------- launch ----------------

extern "C" void kernel_launch(void* const* d_in, const int* in_sizes, int n_in,
                              void* d_out, int out_size, void* d_ws, size_t ws_size,
                              hipStream_t stream) {
    const float* x    = (const float*)d_in[0];
    const int*   eidx = (const int*)d_in[1];   // (2,E) row-major: [src | dst]
    const float* Wl1  = (const float*)d_in[2];
    const float* Wr1  = (const float*)d_in[3];
    const float* att1 = (const float*)d_in[4];
    const float* b1   = (const float*)d_in[5];
    const float* Wl2  = (const float*)d_in[6];
    const float* Wr2  = (const float*)d_in[7];
    const float* att2 = (const float*)d_in[8];
    const float* b2   = (const float*)d_in[9];
    const float* Wfc  = (const float*)d_in[10];
    const float* bfc  = (const float*)d_in[11];
    float* out = (float*)d_out;

    const int* srcv = eidx;
    const int* dstv = eidx + Ee;

    // workspace layout
    size_t NHC = (size_t)Nn * HC;
    float* XR = (float*)d_ws;
    float* gpart = XR + NHC;                   // 32*256 pooling slices
    unsigned short* XLh = (unsigned short*)(gpart + 32 * 256);
    short* Ah   = (short*)(XLh + NHC);
    short* Al   = Ah + NHC;
    short* WhT1 = Al + NHC;                    // 512*256 concat [Wl|Wr]^T per layer
    short* WlT1 = WhT1 + 512 * 256;
    short* WhT2 = WlT1 + 512 * 256;
    short* WlT2 = WhT2 + 512 * 256;
    int* deg       = (int*)(WlT2 + 512 * 256);
    int* row_start = deg + Nn;
    int* cursor    = row_start + (Nn + 1);
    int* colx      = cursor + Nn;              // Ee + Nn entries
    int* bsum      = colx + (Ee + Nn);
    int* boff      = bsum + 128;               // NB_+1 entries

    const int N4 = (int)(NHC / 4);             // 320000

    // 1) weight transpose-split + x split (one dispatch)
    prep<<<64 + (N4 + 255) / 256, 256, 0, stream>>>(x, Wl1, Wr1, Wl2, Wr2,
                                                    Ah, Al, WhT1, WlT1, WhT2, WlT2, N4);

    // 2) CSR build (multi-dispatch chain)
    init_deg<<<(Nn + 255) / 256, 256, 0, stream>>>(deg, gpart, Nn);
    hist_kernel<<<(Ee + 255) / 256, 256, 0, stream>>>(dstv, Ee, deg);
    scan1<<<NB_, 256, 0, stream>>>(deg, row_start, bsum, Nn);
    scan2<<<1, 64, 0, stream>>>(bsum, boff, NB_);
    scan_add<<<(Nn + 256) / 256, 256, 0, stream>>>(row_start, cursor, boff, Nn, NB_);
    scatter_kernel<<<(Ee + Nn + 255) / 256, 256, 0, stream>>>(srcv, dstv, Ee, Nn, cursor, colx);

    const int GB = 8 * 79;                     // 632 blocks, %8 == 0

    // 3) layer 1
    mfma_gemm<<<GB, 256, 0, stream>>>(Ah, Al, WhT1, WlT1, XLh, XR);
    gat_kernel<<<Nn / 4, 256, 0, stream>>>((const ushort4*)XLh, (const float4*)XR,
                                           row_start, colx, (const float4*)att1,
                                           (const float4*)b1, gpart,
                                           (short4*)Ah, (short4*)Al, 1);

    // 4) layer 2 (gat fuses pooling into gpart)
    mfma_gemm<<<GB, 256, 0, stream>>>(Ah, Al, WhT2, WlT2, XLh, XR);
    gat_kernel<<<Nn / 4, 256, 0, stream>>>((const ushort4*)XLh, (const float4*)XR,
                                           row_start, colx, (const float4*)att2,
                                           (const float4*)b2, gpart,
                                           (short4*)Ah, (short4*)Al, 0);

    // 5) FC
    fc_kernel<<<1, 256, 0, stream>>>(gpart, Wfc, bfc, out, 1.0f / Nn);
}